// Round 6
// baseline (282.371 us; speedup 1.0000x reference)
//
#include <hip/hip_runtime.h>
#include <hip/hip_cooperative_groups.h>
#include <stdint.h>

namespace cg = cooperative_groups;

#define NBINS 1000
#define GRID 512
#define BLK 256
#define HISTOFF 4096  // uint offset of global histograms in W

typedef float vf4 __attribute__((ext_vector_type(4)));

// ---- sortable encoding for f32 min/max ----
__device__ __forceinline__ unsigned enc_f32(float f) {
    unsigned b = __float_as_uint(f);
    return (b & 0x80000000u) ? ~b : (b | 0x80000000u);
}
__device__ __forceinline__ float dec_f32(unsigned e) {
    unsigned b = (e & 0x80000000u) ? (e ^ 0x80000000u) : ~e;
    return __uint_as_float(b);
}

// count of v <= x_j == sum_{k<=j} hist[k] with bin k = clamp(ceil((v-lo)/dx))
__device__ __forceinline__ int binof(float v, float lo, float inv_dx) {
    float u = (v - lo) * inv_dx;
    int k = (int)ceilf(u);
    return min(max(k, 0), NBINS - 1);
}

__device__ __forceinline__ vf4 ntload(const vf4* a) {
    return __builtin_nontemporal_load(a);
}

#define MM1(v) { unsigned e = enc_f32(v); emin = min(emin, e); emax = max(emax, e); }
#define MM4(q) { MM1(q.x) MM1(q.y) MM1(q.z) MM1(q.w) }

// W layout (uints): [0..GRID)=per-block min, [GRID..2*GRID)=per-block max,
//                   [HISTOFF..HISTOFF+2*NBINS)=global histograms (p then t)
__global__ void __launch_bounds__(BLK) crps_fused(
        const float* __restrict__ p, const float* __restrict__ t,
        long long n, unsigned* __restrict__ W, float* __restrict__ out) {
    cg::grid_group grid = cg::this_grid();

    __shared__ __align__(16) unsigned h[8 * NBINS];  // 32 KB hist copies / reused in phase 3
    __shared__ unsigned sA[BLK];
    __shared__ unsigned sB[BLK];

    const int tid = threadIdx.x;
    const int bid = blockIdx.x;

    // zero this block's 4-word slice of the global histogram region
    {
        int j = bid * 4 + tid;
        if (tid < 4 && j < 2 * NBINS) W[HISTOFF + j] = 0u;
    }

    long long n4 = n >> 2;
    const vf4* p4 = (const vf4*)p;
    const vf4* t4 = (const vf4*)t;
    long long idx = (long long)bid * BLK + tid;
    long long stride = (long long)GRID * BLK;

    // ---------------- phase 1: min/max (nontemporal streaming) ----------------
    unsigned emin = 0xFFFFFFFFu, emax = 0u;
    {
        long long i = idx;
        for (; i < n4; i += stride) {
            vf4 a = ntload(&p4[i]);
            vf4 b = ntload(&t4[i]);
            MM4(a) MM4(b)
        }
        for (long long j = (n4 << 2) + idx; j < n; j += stride) {
            MM1(p[j]) MM1(t[j])
        }
    }
    sA[tid] = emin; sB[tid] = emax;
    __syncthreads();
    for (int s = BLK / 2; s > 0; s >>= 1) {
        if (tid < s) {
            sA[tid] = min(sA[tid], sA[tid + s]);
            sB[tid] = max(sB[tid], sB[tid + s]);
        }
        __syncthreads();
    }
    if (tid == 0) { W[bid] = sA[0]; W[GRID + bid] = sB[0]; }

    grid.sync();

    // ---- every block redundantly reduces the per-block slots (from L2) ----
    {
        unsigned m0 = min(W[tid], W[tid + BLK]);               // GRID = 2*BLK slots
        unsigned m1 = max(W[GRID + tid], W[GRID + tid + BLK]);
        sA[tid] = m0; sB[tid] = m1;
    }
    __syncthreads();
    for (int s = BLK / 2; s > 0; s >>= 1) {
        if (tid < s) {
            sA[tid] = min(sA[tid], sA[tid + s]);
            sB[tid] = max(sB[tid], sB[tid + s]);
        }
        __syncthreads();
    }
    float lo = dec_f32(sA[0]);
    float hi = dec_f32(sB[0]);
    float inv_dx = (float)(NBINS - 1) / (hi - lo);
    __syncthreads();

    // ---------------- phase 2: histogram ----------------
    // 4 LDS sub-copies per histogram (lane&3); copy stride 1000 words = 8-bank
    // rotation so the 4 copies of one bin hit banks {0,8,16,24}.
    for (int i2 = tid; i2 < 8 * NBINS; i2 += BLK) h[i2] = 0u;
    __syncthreads();
    int cpo = (tid & 3) * NBINS;
    int cto = cpo + 4 * NBINS;
    {
        long long i = idx;
        for (; i < n4; i += stride) {
            vf4 a = ntload(&p4[i]);
            vf4 b = ntload(&t4[i]);
            atomicAdd(&h[cpo + binof(a.x, lo, inv_dx)], 1u);
            atomicAdd(&h[cpo + binof(a.y, lo, inv_dx)], 1u);
            atomicAdd(&h[cpo + binof(a.z, lo, inv_dx)], 1u);
            atomicAdd(&h[cpo + binof(a.w, lo, inv_dx)], 1u);
            atomicAdd(&h[cto + binof(b.x, lo, inv_dx)], 1u);
            atomicAdd(&h[cto + binof(b.y, lo, inv_dx)], 1u);
            atomicAdd(&h[cto + binof(b.z, lo, inv_dx)], 1u);
            atomicAdd(&h[cto + binof(b.w, lo, inv_dx)], 1u);
        }
        for (long long j = (n4 << 2) + idx; j < n; j += stride) {
            atomicAdd(&h[cpo + binof(p[j], lo, inv_dx)], 1u);
            atomicAdd(&h[cto + binof(t[j], lo, inv_dx)], 1u);
        }
    }
    __syncthreads();
    {
        unsigned* Wh = W + HISTOFF;
        for (int b = tid; b < NBINS; b += BLK) {
            unsigned sp = h[b] + h[NBINS + b] + h[2 * NBINS + b] + h[3 * NBINS + b];
            unsigned st = h[4 * NBINS + b] + h[5 * NBINS + b] + h[6 * NBINS + b] + h[7 * NBINS + b];
            if (sp) atomicAdd(&Wh[b], sp);
            if (st) atomicAdd(&Wh[NBINS + b], st);
        }
    }

    grid.sync();

    // ---------------- phase 3: block 0 scans + trapz ----------------
    if (bid != 0) return;

    const unsigned* Hp = W + HISTOFF;
    const unsigned* Ht = W + HISTOFF + NBINS;
    // thread t covers bins 4t..4t+3 (NBINS = 4*250, threads 250..255 idle)
    unsigned hp[4] = {0u, 0u, 0u, 0u}, ht[4] = {0u, 0u, 0u, 0u};
    if (4 * tid < NBINS) {
        for (int k = 0; k < 4; ++k) {
            int j = 4 * tid + k;
            hp[k] = Hp[j];
            ht[k] = Ht[j];
        }
    }
    unsigned sumP = hp[0] + hp[1] + hp[2] + hp[3];
    unsigned sumT = ht[0] + ht[1] + ht[2] + ht[3];

    // inclusive block scan of per-thread sums (P)
    sA[tid] = sumP;
    __syncthreads();
    for (int off = 1; off < BLK; off <<= 1) {
        unsigned v = (tid >= off) ? sA[tid - off] : 0u;
        __syncthreads();
        sA[tid] += v;
        __syncthreads();
    }
    unsigned exP = sA[tid] - sumP;
    __syncthreads();
    // inclusive block scan (T)
    sA[tid] = sumT;
    __syncthreads();
    for (int off = 1; off < BLK; off <<= 1) {
        unsigned v = (tid >= off) ? sA[tid - off] : 0u;
        __syncthreads();
        sA[tid] += v;
        __syncthreads();
    }
    unsigned exT = sA[tid] - sumT;

    float invn = 1.0f / (float)n;
    double acc = 0.0;
    if (4 * tid < NBINS) {
        unsigned cp = exP, ct = exT;
        for (int k = 0; k < 4; ++k) {
            int j = 4 * tid + k;
            cp += hp[k];
            ct += ht[k];
            float d = (float)cp * invn - (float)ct * invn;
            float w = (j == 0 || j == NBINS - 1) ? 0.5f : 1.0f;
            acc += (double)(d * d) * (double)w;
        }
    }
    double* rd = (double*)h;  // h unused in phase 3; 16B-aligned
    rd[tid] = acc;
    __syncthreads();
    for (int s = BLK / 2; s > 0; s >>= 1) {
        if (tid < s) rd[tid] += rd[tid + s];
        __syncthreads();
    }
    if (tid == 0) {
        double dx = (double)(hi - lo) / (double)(NBINS - 1);
        out[0] = (float)(rd[0] * dx);
    }
}

extern "C" void kernel_launch(void* const* d_in, const int* in_sizes, int n_in,
                              void* d_out, int out_size, void* d_ws, size_t ws_size,
                              hipStream_t stream) {
    const float* p = (const float*)d_in[0];
    const float* t = (const float*)d_in[1];
    float* out = (float*)d_out;
    long long n = (long long)in_sizes[0];
    unsigned* W = (unsigned*)d_ws;

    void* args[] = { (void*)&p, (void*)&t, (void*)&n, (void*)&W, (void*)&out };
    (void)hipLaunchCooperativeKernel((const void*)crps_fused, dim3(GRID), dim3(BLK),
                                     args, 0, stream);
}